// Round 1
// baseline (5313.661 us; speedup 1.0000x reference)
//
#include <hip/hip_runtime.h>
#include <hip/hip_fp16.h>

typedef _Float16 half8 __attribute__((ext_vector_type(8)));
typedef float f32x4 __attribute__((ext_vector_type(4)));

#define NSTEP 48
#define MT 32      // batch rows per workgroup
#define LDH 264    // LDS h stride in fp16 elements (264*2=528B = 33*16 -> 16B aligned rows, 2-way bank alias = free)

__device__ __forceinline__ float sigm(float x) { return 1.0f / (1.0f + __expf(-x)); }
__device__ __forceinline__ float tanh_f(float x) {
  float ax = fabsf(x);
  float e = __expf(-2.0f * ax);          // in (0,1], no overflow
  float t = (1.0f - e) / (1.0f + e);
  return copysignf(t, x);
}

// Pack weights: W0h[n][0:256]=W_ih0 feature cols, [256:512]=W_hh0 ; W1h[n][0:256]=W_ih1, [256:512]=W_hh1 (fp16).
// b0 = b_ih0+b_hh0, b1 = b_ih1+b_hh1 (fp32). Notes cols (W_ih0[:,256:259]) stay fp32, handled by VALU rank-3 update.
__global__ void prep_weights(const float* __restrict__ Wih0, const float* __restrict__ Whh0,
                             const float* __restrict__ bih0, const float* __restrict__ bhh0,
                             const float* __restrict__ Wih1, const float* __restrict__ Whh1,
                             const float* __restrict__ bih1, const float* __restrict__ bhh1,
                             _Float16* __restrict__ W0h, _Float16* __restrict__ W1h,
                             float* __restrict__ b0, float* __restrict__ b1) {
  int t = blockIdx.x * 256 + threadIdx.x;   // grid covers 1024*512
  int n = t >> 9;
  int k = t & 511;
  float v0 = (k < 256) ? Wih0[n * 259 + k] : Whh0[n * 256 + (k - 256)];
  W0h[n * 512 + k] = (_Float16)v0;
  float v1 = (k < 256) ? Wih1[n * 256 + k] : Whh1[n * 256 + (k - 256)];
  W1h[n * 512 + k] = (_Float16)v1;
  if (t < 1024) b0[t] = bih0[t] + bhh0[t];
  else if (t < 2048) { int i = t - 1024; b1[i] = bih1[i] + bhh1[i]; }
}

__global__ __launch_bounds__(256, 1)
void noteaxis_main(const float* __restrict__ nf, const float* __restrict__ cond,
                   const float* __restrict__ Wih0f, const _Float16* __restrict__ W0h,
                   const _Float16* __restrict__ W1h, const float* __restrict__ b0g,
                   const float* __restrict__ b1g, const float* __restrict__ Wout,
                   const float* __restrict__ bout, float* __restrict__ out) {
  __shared__ __align__(16) _Float16 lds_h0[MT][LDH];
  __shared__ __align__(16) _Float16 lds_h1[MT][LDH];
  __shared__ float lds_part[4][MT][3];
  __shared__ float lds_sn[MT][4];

  const int tid = threadIdx.x;
  const int v = tid >> 6;        // wave id -> owns units [v*64, v*64+64)
  const int lane = tid & 63;
  const int r = lane & 15;       // MFMA row/col-in-tile
  const int q = lane >> 4;       // MFMA quad
  const int row0 = blockIdx.x * MT;

  // zero h state in LDS
  for (int i = tid; i < MT * LDH; i += 256) {
    ((_Float16*)lds_h0)[i] = (_Float16)0.0f;
    ((_Float16*)lds_h1)[i] = (_Float16)0.0f;
  }

  // Hoisted per-lane constants
  float bias0[4][4], bias1[4][4];   // [gate c][unit tile t], col = n0 + r
  float w3[4][4][3];                // notes columns of W_ih0
#pragma unroll
  for (int c = 0; c < 4; ++c)
#pragma unroll
    for (int t = 0; t < 4; ++t) {
      int nrow = c * 256 + v * 64 + t * 16 + r;
      bias0[c][t] = b0g[nrow];
      bias1[c][t] = b1g[nrow];
      w3[c][t][0] = Wih0f[nrow * 259 + 256];
      w3[c][t][1] = Wih0f[nrow * 259 + 257];
      w3[c][t][2] = Wih0f[nrow * 259 + 258];
    }
  float woutv[3][4];                // W_out[ch][u], u = v*64 + t*16 + r
#pragma unroll
  for (int ch = 0; ch < 3; ++ch)
#pragma unroll
    for (int t = 0; t < 4; ++t)
      woutv[ch][t] = Wout[ch * 256 + v * 64 + t * 16 + r];

  // c-state in registers: [mt][t][reg] -> (m = mt*16 + q*4 + reg, u = v*64 + t*16 + r)
  float c0s[2][4][4], c1s[2][4][4];
#pragma unroll
  for (int mt = 0; mt < 2; ++mt)
#pragma unroll
    for (int t = 0; t < 4; ++t)
#pragma unroll
      for (int g = 0; g < 4; ++g) { c0s[mt][t][g] = 0.0f; c1s[mt][t][g] = 0.0f; }

  __syncthreads();

#pragma unroll 1
  for (int n = 0; n < NSTEP; ++n) {
    // ---- stage shifted condition notes for this step ----
    if (tid < MT) {
      float s0 = 0.f, s1 = 0.f, s2 = 0.f;
      if (n > 0) {
        const float* cp = cond + ((size_t)(row0 + tid) * NSTEP + (n - 1)) * 3;
        s0 = cp[0]; s1 = cp[1]; s2 = cp[2];
      }
      lds_sn[tid][0] = s0; lds_sn[tid][1] = s1; lds_sn[tid][2] = s2;
    }
    __syncthreads();  // B0

    float snv[2][4][3];
#pragma unroll
    for (int mt = 0; mt < 2; ++mt)
#pragma unroll
      for (int g = 0; g < 4; ++g) {
        int m = mt * 16 + q * 4 + g;
        snv[mt][g][0] = lds_sn[m][0];
        snv[mt][g][1] = lds_sn[m][1];
        snv[mt][g][2] = lds_sn[m][2];
      }

    // ================= Layer 0 GEMM: gates = [x_feat, h0] @ W0cat^T + b0 =================
    f32x4 acc[2][4][4];
#pragma unroll
    for (int c = 0; c < 4; ++c)
#pragma unroll
      for (int t = 0; t < 4; ++t) {
        f32x4 bz = {bias0[c][t], bias0[c][t], bias0[c][t], bias0[c][t]};
        acc[0][c][t] = bz; acc[1][c][t] = bz;
      }

    // x-feature part (K tiles 0..7), A from global fp32 -> fp16
#pragma unroll 2
    for (int kt = 0; kt < 8; ++kt) {
      half8 a[2];
#pragma unroll
      for (int mt = 0; mt < 2; ++mt) {
        const float* ap = nf + ((size_t)(row0 + mt * 16 + r) * NSTEP + n) * 256 + kt * 32 + q * 8;
        float4 x0 = *(const float4*)ap;
        float4 x1 = *(const float4*)(ap + 4);
        half8 ah;
        ah[0] = (_Float16)x0.x; ah[1] = (_Float16)x0.y; ah[2] = (_Float16)x0.z; ah[3] = (_Float16)x0.w;
        ah[4] = (_Float16)x1.x; ah[5] = (_Float16)x1.y; ah[6] = (_Float16)x1.z; ah[7] = (_Float16)x1.w;
        a[mt] = ah;
      }
#pragma unroll
      for (int c = 0; c < 4; ++c)
#pragma unroll
        for (int t = 0; t < 4; ++t) {
          const half8 b = *(const half8*)(W0h + (size_t)(c * 256 + v * 64 + t * 16 + r) * 512 + kt * 32 + q * 8);
          acc[0][c][t] = __builtin_amdgcn_mfma_f32_16x16x32_f16(a[0], b, acc[0][c][t], 0, 0, 0);
          acc[1][c][t] = __builtin_amdgcn_mfma_f32_16x16x32_f16(a[1], b, acc[1][c][t], 0, 0, 0);
        }
    }
    // h0 recurrent part (K tiles 8..15), A from LDS
#pragma unroll 2
    for (int kt = 0; kt < 8; ++kt) {
      half8 a[2];
      a[0] = *(const half8*)&lds_h0[r][kt * 32 + q * 8];
      a[1] = *(const half8*)&lds_h0[16 + r][kt * 32 + q * 8];
#pragma unroll
      for (int c = 0; c < 4; ++c)
#pragma unroll
        for (int t = 0; t < 4; ++t) {
          const half8 b = *(const half8*)(W0h + (size_t)(c * 256 + v * 64 + t * 16 + r) * 512 + 256 + kt * 32 + q * 8);
          acc[0][c][t] = __builtin_amdgcn_mfma_f32_16x16x32_f16(a[0], b, acc[0][c][t], 0, 0, 0);
          acc[1][c][t] = __builtin_amdgcn_mfma_f32_16x16x32_f16(a[1], b, acc[1][c][t], 0, 0, 0);
        }
    }
    // rank-3 shifted-notes update (VALU)
#pragma unroll
    for (int mt = 0; mt < 2; ++mt)
#pragma unroll
      for (int c = 0; c < 4; ++c)
#pragma unroll
        for (int t = 0; t < 4; ++t)
#pragma unroll
          for (int g = 0; g < 4; ++g)
            acc[mt][c][t][g] += snv[mt][g][0] * w3[c][t][0] + snv[mt][g][1] * w3[c][t][1] + snv[mt][g][2] * w3[c][t][2];

    __syncthreads();  // B1: all waves done reading lds_h0

    // ---- cell 0 ----
#pragma unroll
    for (int mt = 0; mt < 2; ++mt)
#pragma unroll
      for (int t = 0; t < 4; ++t)
#pragma unroll
        for (int g = 0; g < 4; ++g) {
          float i_ = acc[mt][0][t][g], f_ = acc[mt][1][t][g], g_ = acc[mt][2][t][g], o_ = acc[mt][3][t][g];
          float cc = sigm(f_) * c0s[mt][t][g] + sigm(i_) * tanh_f(g_);
          c0s[mt][t][g] = cc;
          float hh = sigm(o_) * tanh_f(cc);
          lds_h0[mt * 16 + q * 4 + g][v * 64 + t * 16 + r] = (_Float16)hh;
        }
    __syncthreads();  // B2: h0 new visible

    // ================= Layer 1 GEMM: gates = [h0n, h1] @ W1cat^T + b1 =================
#pragma unroll
    for (int c = 0; c < 4; ++c)
#pragma unroll
      for (int t = 0; t < 4; ++t) {
        f32x4 bz = {bias1[c][t], bias1[c][t], bias1[c][t], bias1[c][t]};
        acc[0][c][t] = bz; acc[1][c][t] = bz;
      }
#pragma unroll 2
    for (int kt = 0; kt < 8; ++kt) {
      half8 a[2];
      a[0] = *(const half8*)&lds_h0[r][kt * 32 + q * 8];
      a[1] = *(const half8*)&lds_h0[16 + r][kt * 32 + q * 8];
#pragma unroll
      for (int c = 0; c < 4; ++c)
#pragma unroll
        for (int t = 0; t < 4; ++t) {
          const half8 b = *(const half8*)(W1h + (size_t)(c * 256 + v * 64 + t * 16 + r) * 512 + kt * 32 + q * 8);
          acc[0][c][t] = __builtin_amdgcn_mfma_f32_16x16x32_f16(a[0], b, acc[0][c][t], 0, 0, 0);
          acc[1][c][t] = __builtin_amdgcn_mfma_f32_16x16x32_f16(a[1], b, acc[1][c][t], 0, 0, 0);
        }
    }
#pragma unroll 2
    for (int kt = 0; kt < 8; ++kt) {
      half8 a[2];
      a[0] = *(const half8*)&lds_h1[r][kt * 32 + q * 8];
      a[1] = *(const half8*)&lds_h1[16 + r][kt * 32 + q * 8];
#pragma unroll
      for (int c = 0; c < 4; ++c)
#pragma unroll
        for (int t = 0; t < 4; ++t) {
          const half8 b = *(const half8*)(W1h + (size_t)(c * 256 + v * 64 + t * 16 + r) * 512 + 256 + kt * 32 + q * 8);
          acc[0][c][t] = __builtin_amdgcn_mfma_f32_16x16x32_f16(a[0], b, acc[0][c][t], 0, 0, 0);
          acc[1][c][t] = __builtin_amdgcn_mfma_f32_16x16x32_f16(a[1], b, acc[1][c][t], 0, 0, 0);
        }
    }
    __syncthreads();  // B3: all waves done reading lds_h0/lds_h1

    // ---- cell 1 + output-projection partials ----
    float part[2][4][3];
#pragma unroll
    for (int mt = 0; mt < 2; ++mt)
#pragma unroll
      for (int g = 0; g < 4; ++g) { part[mt][g][0] = 0.f; part[mt][g][1] = 0.f; part[mt][g][2] = 0.f; }

#pragma unroll
    for (int mt = 0; mt < 2; ++mt)
#pragma unroll
      for (int t = 0; t < 4; ++t)
#pragma unroll
        for (int g = 0; g < 4; ++g) {
          float i_ = acc[mt][0][t][g], f_ = acc[mt][1][t][g], g_ = acc[mt][2][t][g], o_ = acc[mt][3][t][g];
          float cc = sigm(f_) * c1s[mt][t][g] + sigm(i_) * tanh_f(g_);
          c1s[mt][t][g] = cc;
          float hh = sigm(o_) * tanh_f(cc);
          lds_h1[mt * 16 + q * 4 + g][v * 64 + t * 16 + r] = (_Float16)hh;
          part[mt][g][0] += hh * woutv[0][t];
          part[mt][g][1] += hh * woutv[1][t];
          part[mt][g][2] += hh * woutv[2][t];
        }
    // reduce over the 16 lanes (u within wave slice)
#pragma unroll
    for (int mt = 0; mt < 2; ++mt)
#pragma unroll
      for (int g = 0; g < 4; ++g)
#pragma unroll
        for (int ch = 0; ch < 3; ++ch) {
          float p = part[mt][g][ch];
          p += __shfl_xor(p, 1);
          p += __shfl_xor(p, 2);
          p += __shfl_xor(p, 4);
          p += __shfl_xor(p, 8);
          part[mt][g][ch] = p;
        }
    if (r == 0) {
#pragma unroll
      for (int mt = 0; mt < 2; ++mt)
#pragma unroll
        for (int g = 0; g < 4; ++g) {
          int m = mt * 16 + q * 4 + g;
          lds_part[v][m][0] = part[mt][g][0];
          lds_part[v][m][1] = part[mt][g][1];
          lds_part[v][m][2] = part[mt][g][2];
        }
    }
    __syncthreads();  // B4

    if (tid < 96) {
      int m = tid / 3;
      int ch = tid - m * 3;
      float s = lds_part[0][m][ch] + lds_part[1][m][ch] + lds_part[2][m][ch] + lds_part[3][m][ch] + bout[ch];
      if (ch < 2) s = 1.0f / (1.0f + __expf(-s));
      out[((size_t)(row0 + m) * NSTEP + n) * 3 + ch] = s;
    }
    // next-iteration lds_sn/lds_part writes are fenced by B0/B3 of the next step
  }
}

extern "C" void kernel_launch(void* const* d_in, const int* in_sizes, int n_in,
                              void* d_out, int out_size, void* d_ws, size_t ws_size,
                              hipStream_t stream) {
  const float* nf   = (const float*)d_in[0];
  const float* cond = (const float*)d_in[1];
  const float* Wih0 = (const float*)d_in[2];
  const float* Whh0 = (const float*)d_in[3];
  const float* bih0 = (const float*)d_in[4];
  const float* bhh0 = (const float*)d_in[5];
  const float* Wih1 = (const float*)d_in[6];
  const float* Whh1 = (const float*)d_in[7];
  const float* bih1 = (const float*)d_in[8];
  const float* bhh1 = (const float*)d_in[9];
  const float* Wout = (const float*)d_in[10];
  const float* bout = (const float*)d_in[11];
  float* out = (float*)d_out;

  _Float16* W0h = (_Float16*)d_ws;                 // 1024*512 fp16 = 1 MB
  _Float16* W1h = W0h + 1024 * 512;                // 1 MB
  float* b0 = (float*)(W1h + 1024 * 512);          // 4 KB
  float* b1 = b0 + 1024;                           // 4 KB

  prep_weights<<<2048, 256, 0, stream>>>(Wih0, Whh0, bih0, bhh0, Wih1, Whh1, bih1, bhh1, W0h, W1h, b0, b1);
  noteaxis_main<<<128, 256, 0, stream>>>(nf, cond, Wih0, W0h, W1h, b0, b1, Wout, bout, out);
}

// Round 2
// 2788.811 us; speedup vs baseline: 1.9053x; 1.9053x over previous
//
#include <hip/hip_runtime.h>

typedef _Float16 half8 __attribute__((ext_vector_type(8)));
typedef float f32x4 __attribute__((ext_vector_type(4)));

#define NSTEP 48
#define MT 16          // batch rows per workgroup (256 wgs cover 4096)
#define W0S 544        // W0 packed row stride: 256 x-feat | 256 h0 | 3 notes | 29 zero pad
#define W1S 512        // W1 packed row stride: 256 h0new | 256 h1
#define LDH0 296       // lds_h0 row stride (fp16): 256 h + 32 ext (sn+zeros) + pad; 148 words % 32 = 20 -> 2-way
#define LDH1 264       // lds_h1 row stride; 132 words % 32 = 4 -> 2-way

__device__ __forceinline__ float sigm(float x) { return 1.0f / (1.0f + __expf(-x)); }
__device__ __forceinline__ float tanh_f(float x) {
  float ax = fabsf(x);
  float e = __expf(-2.0f * ax);
  float t = (1.0f - e) / (1.0f + e);
  return copysignf(t, x);
}

// Pack weights (fp16):
//   W0h[n][0:256]   = W_ih0[n][0:256] (features)
//   W0h[n][256:512] = W_hh0[n]
//   W0h[n][512:515] = W_ih0[n][256:259] (shifted-note cols), [515:544) = 0
//   W1h[n][0:256]   = W_ih1[n],  W1h[n][256:512] = W_hh1[n]
//   b0 = b_ih0 + b_hh0, b1 = b_ih1 + b_hh1 (fp32)
__global__ void prep_weights(const float* __restrict__ Wih0, const float* __restrict__ Whh0,
                             const float* __restrict__ bih0, const float* __restrict__ bhh0,
                             const float* __restrict__ Wih1, const float* __restrict__ Whh1,
                             const float* __restrict__ bih1, const float* __restrict__ bhh1,
                             _Float16* __restrict__ W0h, _Float16* __restrict__ W1h,
                             float* __restrict__ b0, float* __restrict__ b1) {
  int n = blockIdx.x;      // 1024
  int k = threadIdx.x;     // 256
  W0h[n * W0S + k]       = (_Float16)Wih0[n * 259 + k];
  W0h[n * W0S + 256 + k] = (_Float16)Whh0[n * 256 + k];
  if (k < 32) W0h[n * W0S + 512 + k] = (k < 3) ? (_Float16)Wih0[n * 259 + 256 + k] : (_Float16)0.0f;
  W1h[n * W1S + k]       = (_Float16)Wih1[n * 256 + k];
  W1h[n * W1S + 256 + k] = (_Float16)Whh1[n * 256 + k];
  if (k == 0) { b0[n] = bih0[n] + bhh0[n]; b1[n] = bih1[n] + bhh1[n]; }
}

__global__ __launch_bounds__(256, 1)
void noteaxis_main(const float* __restrict__ nf, const float* __restrict__ cond,
                   const _Float16* __restrict__ W0h, const _Float16* __restrict__ W1h,
                   const float* __restrict__ b0g, const float* __restrict__ b1g,
                   const float* __restrict__ Wout, const float* __restrict__ bout,
                   float* __restrict__ out) {
  __shared__ __align__(16) _Float16 lds_h0[MT][LDH0];
  __shared__ __align__(16) _Float16 lds_h1[MT][LDH1];
  __shared__ float lds_b0[1024];
  __shared__ float lds_b1[1024];
  __shared__ float lds_part[4][MT][3];

  const int tid = threadIdx.x;
  const int v = tid >> 6;        // wave: owns units [v*64, v*64+64)
  const int lane = tid & 63;
  const int r = lane & 15;
  const int q = lane >> 4;
  const int row0 = blockIdx.x * MT;

  for (int i = tid; i < MT * LDH0; i += 256) ((_Float16*)lds_h0)[i] = (_Float16)0.0f;
  for (int i = tid; i < MT * LDH1; i += 256) ((_Float16*)lds_h1)[i] = (_Float16)0.0f;
  for (int i = tid; i < 1024; i += 256) { lds_b0[i] = b0g[i]; lds_b1[i] = b1g[i]; }

  const int u0 = v * 64 + r;     // unit/gate column for this lane within its 64-slice
  const _Float16* pB0 = W0h + (size_t)u0 * W0S + q * 8;
  const _Float16* pB1 = W1h + (size_t)u0 * W1S + q * 8;
  const float* pXrow = nf + (size_t)(row0 + r) * NSTEP * 256 + q * 8;

  float wov[3][4];
#pragma unroll
  for (int ch = 0; ch < 3; ++ch)
#pragma unroll
    for (int t = 0; t < 4; ++t)
      wov[ch][t] = Wout[ch * 256 + v * 64 + t * 16 + r];
  const float bo0 = bout[0], bo1 = bout[1], bo2 = bout[2];

  float c0s[4][4], c1s[4][4];    // [t][g]; batch row m = q*4+g, unit u = v*64+t*16+r
#pragma unroll
  for (int t = 0; t < 4; ++t)
#pragma unroll
    for (int g = 0; g < 4; ++g) { c0s[t][g] = 0.0f; c1s[t][g] = 0.0f; }

  f32x4 acc[16];                 // [ct] ct = c*4+t (c = gate i/f/g/o)
  half8 Bb[2][8];                // double-buffered half-kt B chunks

  auto loadB0 = [&](half8* d, const _Float16* pt, int cb) {
#pragma unroll
    for (int j = 0; j < 8; ++j) {
      int ct = cb + j;
      d[j] = *(const half8*)(pt + ((ct >> 2) * 256 + (ct & 3) * 16) * W0S);
    }
  };
  auto loadB1 = [&](half8* d, const _Float16* pt, int cb) {
#pragma unroll
    for (int j = 0; j < 8; ++j) {
      int ct = cb + j;
      d[j] = *(const half8*)(pt + ((ct >> 2) * 256 + (ct & 3) * 16) * W1S);
    }
  };
  auto mfma8 = [&](half8 a, half8* B, int cb) {
#pragma unroll
    for (int j = 0; j < 8; ++j)
      acc[cb + j] = __builtin_amdgcn_mfma_f32_16x16x32_f16(a, B[j], acc[cb + j], 0, 0, 0);
  };

  __syncthreads();

  loadB0(Bb[0], pB0, 0);         // prologue: (L0 kt0, lo) for step 0

#pragma unroll 1
  for (int n = 0; n < NSTEP; ++n) {
    // ---- stage shifted condition notes into lds_h0 extension cols [256..259) ----
    if (tid < MT) {
      float s0 = 0.f, s1 = 0.f, s2 = 0.f;
      if (n > 0) {
        const float* cp = cond + ((size_t)(row0 + tid) * NSTEP + (n - 1)) * 3;
        s0 = cp[0]; s1 = cp[1]; s2 = cp[2];
      }
      lds_h0[tid][256] = (_Float16)s0;
      lds_h0[tid][257] = (_Float16)s1;
      lds_h0[tid][258] = (_Float16)s2;
    }
    __syncthreads();  // B0

    // acc init = bias0
#pragma unroll
    for (int ct = 0; ct < 16; ++ct) {
      float b = lds_b0[(ct >> 2) * 256 + (ct & 3) * 16 + u0];
      f32x4 bz = {b, b, b, b};
      acc[ct] = bz;
    }

    // ================= Layer 0: x-feature part, kt 0..7 =================
    const float* px = pXrow + n * 256;
    float4 xA = *(const float4*)px;
    float4 xB = *(const float4*)(px + 4);
    const _Float16* pt0 = pB0;
#pragma unroll 1
    for (int kt = 0; kt < 8; ++kt) {
      half8 a;
      a[0] = (_Float16)xA.x; a[1] = (_Float16)xA.y; a[2] = (_Float16)xA.z; a[3] = (_Float16)xA.w;
      a[4] = (_Float16)xB.x; a[5] = (_Float16)xB.y; a[6] = (_Float16)xB.z; a[7] = (_Float16)xB.w;
      if (kt < 7) {
        xA = *(const float4*)(px + (kt + 1) * 32);
        xB = *(const float4*)(px + (kt + 1) * 32 + 4);
      }
      loadB0(Bb[1], pt0, 8);                 // hi chunk of this kt
      mfma8(a, Bb[0], 0);
      if (kt < 7) loadB0(Bb[0], pt0 + 32, 0);   // lo chunk of next kt
      else        loadB0(Bb[0], pB0 + 256, 0);  // seam: lo chunk of h-part kt0
      mfma8(a, Bb[1], 8);
      pt0 += 32;
    }
    // ================= Layer 0: h0 + notes part, kt 0..8 (kt==8 is the sn extension) =================
    const _Float16* pth = pB0 + 256;
#pragma unroll 1
    for (int kt = 0; kt < 9; ++kt) {
      half8 a = *(const half8*)&lds_h0[r][kt * 32 + q * 8];   // kt==8 -> cols 256..287 = [sn, zeros]
      loadB0(Bb[1], pth, 8);
      mfma8(a, Bb[0], 0);
      if (kt < 8) loadB0(Bb[0], pth + 32, 0);
      mfma8(a, Bb[1], 8);
      pth += 32;
    }
    loadB1(Bb[0], pB1, 0);        // prefetch L1 kt0 lo across the barrier region

    __syncthreads();  // B1: all waves done reading lds_h0 (h0(n-1) + sn)

    // ---- cell 0 ----
#pragma unroll
    for (int t = 0; t < 4; ++t)
#pragma unroll
      for (int g = 0; g < 4; ++g) {
        float i_ = acc[t][g], f_ = acc[4 + t][g], g_ = acc[8 + t][g], o_ = acc[12 + t][g];
        float cc = sigm(f_) * c0s[t][g] + sigm(i_) * tanh_f(g_);
        c0s[t][g] = cc;
        lds_h0[q * 4 + g][v * 64 + t * 16 + r] = (_Float16)(sigm(o_) * tanh_f(cc));
      }
    __syncthreads();  // B2: h0(n) visible

    // acc init = bias1
#pragma unroll
    for (int ct = 0; ct < 16; ++ct) {
      float b = lds_b1[(ct >> 2) * 256 + (ct & 3) * 16 + u0];
      f32x4 bz = {b, b, b, b};
      acc[ct] = bz;
    }

    // ================= Layer 1: h0new part kt 0..7, then h1 part kt 0..7 =================
    const _Float16* pt1 = pB1;
#pragma unroll 1
    for (int kt = 0; kt < 8; ++kt) {
      half8 a = *(const half8*)&lds_h0[r][kt * 32 + q * 8];
      loadB1(Bb[1], pt1, 8);
      mfma8(a, Bb[0], 0);
      loadB1(Bb[0], pt1 + 32, 0);            // kt==7 -> pB1+256 = h1-part kt0 lo (seamless)
      mfma8(a, Bb[1], 8);
      pt1 += 32;
    }
#pragma unroll 1
    for (int kt = 0; kt < 8; ++kt) {
      half8 a = *(const half8*)&lds_h1[r][kt * 32 + q * 8];
      loadB1(Bb[1], pt1, 8);
      mfma8(a, Bb[0], 0);
      if (kt < 7) loadB1(Bb[0], pt1 + 32, 0);
      mfma8(a, Bb[1], 8);
      pt1 += 32;
    }
    loadB0(Bb[0], pB0, 0);        // prefetch next step's L0 kt0 lo

    __syncthreads();  // B3: all waves done reading lds_h0/lds_h1

    // ---- cell 1 + output-projection partials ----
    float part[4][3];
#pragma unroll
    for (int g = 0; g < 4; ++g) { part[g][0] = 0.f; part[g][1] = 0.f; part[g][2] = 0.f; }

#pragma unroll
    for (int t = 0; t < 4; ++t)
#pragma unroll
      for (int g = 0; g < 4; ++g) {
        float i_ = acc[t][g], f_ = acc[4 + t][g], g_ = acc[8 + t][g], o_ = acc[12 + t][g];
        float cc = sigm(f_) * c1s[t][g] + sigm(i_) * tanh_f(g_);
        c1s[t][g] = cc;
        float hh = sigm(o_) * tanh_f(cc);
        lds_h1[q * 4 + g][v * 64 + t * 16 + r] = (_Float16)hh;
        part[g][0] += hh * wov[0][t];
        part[g][1] += hh * wov[1][t];
        part[g][2] += hh * wov[2][t];
      }
#pragma unroll
    for (int g = 0; g < 4; ++g)
#pragma unroll
      for (int ch = 0; ch < 3; ++ch) {
        float p = part[g][ch];
        p += __shfl_xor(p, 1);
        p += __shfl_xor(p, 2);
        p += __shfl_xor(p, 4);
        p += __shfl_xor(p, 8);
        part[g][ch] = p;
      }
    if (r == 0) {
#pragma unroll
      for (int g = 0; g < 4; ++g) {
        int m = q * 4 + g;
        lds_part[v][m][0] = part[g][0];
        lds_part[v][m][1] = part[g][1];
        lds_part[v][m][2] = part[g][2];
      }
    }
    __syncthreads();  // B4

    if (tid < MT * 3) {
      int m = tid / 3;
      int ch = tid - m * 3;
      float s = lds_part[0][m][ch] + lds_part[1][m][ch] + lds_part[2][m][ch] + lds_part[3][m][ch]
              + (ch == 0 ? bo0 : (ch == 1 ? bo1 : bo2));
      if (ch < 2) s = 1.0f / (1.0f + __expf(-s));
      out[((size_t)(row0 + m) * NSTEP + n) * 3 + ch] = s;
    }
  }
}

extern "C" void kernel_launch(void* const* d_in, const int* in_sizes, int n_in,
                              void* d_out, int out_size, void* d_ws, size_t ws_size,
                              hipStream_t stream) {
  const float* nf   = (const float*)d_in[0];
  const float* cond = (const float*)d_in[1];
  const float* Wih0 = (const float*)d_in[2];
  const float* Whh0 = (const float*)d_in[3];
  const float* bih0 = (const float*)d_in[4];
  const float* bhh0 = (const float*)d_in[5];
  const float* Wih1 = (const float*)d_in[6];
  const float* Whh1 = (const float*)d_in[7];
  const float* bih1 = (const float*)d_in[8];
  const float* bhh1 = (const float*)d_in[9];
  const float* Wout = (const float*)d_in[10];
  const float* bout = (const float*)d_in[11];
  float* out = (float*)d_out;

  _Float16* W0h = (_Float16*)d_ws;                       // 1024*544*2 B
  _Float16* W1h = W0h + 1024 * W0S;                      // 1024*512*2 B
  float* b0 = (float*)(W1h + 1024 * W1S);                // 4 KB
  float* b1 = b0 + 1024;                                 // 4 KB

  prep_weights<<<1024, 256, 0, stream>>>(Wih0, Whh0, bih0, bhh0, Wih1, Whh1, bih1, bhh1, W0h, W1h, b0, b1);
  noteaxis_main<<<256, 256, 0, stream>>>(nf, cond, W0h, W1h, b0, b1, Wout, bout, out);
}